// Round 2
// baseline (3645.822 us; speedup 1.0000x reference)
//
#include <hip/hip_runtime.h>
#include <math.h>

#define NTOK 32768
#define NDIM 512
#define NCODE 4096

// output layout (flat f32, reference tuple order)
#define OFF_Z      0
#define OFF_DIFF   16777216
#define OFF_CODES  16777217
#define OFF_EMB    16809985
#define OFF_SIZE   18907137
#define OFF_SUM    18911233
#define OFF_AVGU   21008385
#define OFF_USAGE  21008386
#define OFF_ENT    21008387

#define TAU 0.03f

typedef __bf16 bf16x8 __attribute__((ext_vector_type(8)));
typedef float f32x4 __attribute__((ext_vector_type(4)));
typedef unsigned short ushort8 __attribute__((ext_vector_type(8)));
typedef unsigned int u32;

__device__ __forceinline__ void atomAddF(float* p, float v) {
  unsafeAtomicAdd(p, v);
}

__device__ __forceinline__ void gload16(const void* g, void* l) {
  __builtin_amdgcn_global_load_lds((const __attribute__((address_space(1))) u32*)g,
                                   (__attribute__((address_space(3))) u32*)l, 16, 0, 0);
}

__global__ void k_zero(float* __restrict__ p, int n) {
  int i = blockIdx.x * blockDim.x + threadIdx.x;
  if (i < n) p[i] = 0.0f;
}

// split f32 into bf16 hi + bf16 lo (8 elements / thread)
__global__ void k_split(const float* __restrict__ in, unsigned short* __restrict__ hi,
                        unsigned short* __restrict__ lo, int n8) {
  int i = blockIdx.x * blockDim.x + threadIdx.x;
  if (i >= n8) return;
  const float4* p = (const float4*)(in + (size_t)i * 8);
  float4 a = p[0], b = p[1];
  float v[8] = {a.x, a.y, a.z, a.w, b.x, b.y, b.z, b.w};
  ushort8 h, lw;
  #pragma unroll
  for (int j = 0; j < 8; j++) {
    float f = v[j];
    __bf16 hb = (__bf16)f;
    float hf = (float)hb;
    __bf16 lb = (__bf16)(f - hf);
    h[j]  = __builtin_bit_cast(unsigned short, hb);
    lw[j] = __builtin_bit_cast(unsigned short, lb);
  }
  *(ushort8*)(hi + (size_t)i * 8) = h;
  *(ushort8*)(lo + (size_t)i * 8) = lw;
}

// one wave per row: sum of squares of a 512-float row
__global__ void k_rowsq(const float* __restrict__ rows, float* __restrict__ out, int nrows) {
  int gw   = (blockIdx.x * blockDim.x + threadIdx.x) >> 6;
  int lane = threadIdx.x & 63;
  if (gw >= nrows) return;
  const float* r = rows + (size_t)gw * NDIM + lane * 8;
  float4 a = *(const float4*)r;
  float4 b = *(const float4*)(r + 4);
  float s = ((a.x*a.x + a.y*a.y) + (a.z*a.z + a.w*a.w))
          + ((b.x*b.x + b.y*b.y) + (b.z*b.z + b.w*b.w));
  #pragma unroll
  for (int off = 32; off >= 1; off >>= 1) s += __shfl_xor(s, off, 64);
  if (lane == 0) out[gw] = s;
}

// ===================== MFMA argmin =====================
// block: 256 threads (4 waves, wave grid 2x2), 128 tokens; loops codes in 128-chunks.
// dot = hiX*hiE + hiX*loE + loX*hiE (3 bf16 MFMAs), f32 accumulate.
// tracks per-token top-2 distances; margin written for exact recheck.
__launch_bounds__(256)
__global__ void k_argmin_mfma(const unsigned short* __restrict__ xh, const unsigned short* __restrict__ xl,
                              const unsigned short* __restrict__ eh, const unsigned short* __restrict__ el,
                              const float* __restrict__ x2, const float* __restrict__ e2,
                              int* __restrict__ idxOut, float* __restrict__ marginOut) {
  __shared__ __align__(16) unsigned short Ah[128 * 32];
  __shared__ __align__(16) unsigned short Al[128 * 32];
  __shared__ __align__(16) unsigned short Bh[128 * 32];
  __shared__ __align__(16) unsigned short Bl[128 * 32];
  __shared__ float redD[2][128];
  __shared__ int   redI[2][128];
  __shared__ float redS[2][128];

  const int tid = threadIdx.x;
  const int w   = tid >> 6;
  const int l   = tid & 63;
  const int wm  = w >> 1;     // 0..1 token half
  const int wn  = w & 1;      // 0..1 code half
  const int l15 = l & 15;
  const int l4  = l >> 4;
  const int brow = blockIdx.x * 128;

  // staging assignment: wave w owns one tile
  const unsigned short* gsrc0 = (w == 0) ? xh : (w == 1) ? xl : (w == 2) ? eh : el;
  unsigned short* ldst = (w == 0) ? Ah : (w == 1) ? Al : (w == 2) ? Bh : Bl;
  const bool isB = (w >= 2);
  const int laneRow = l >> 2;
  const int laneK   = (l & 3) * 8;

  // fragment LDS addresses (ushort elements), fixed across iterations
  int aAddr[4], bAddr[4];
  #pragma unroll
  for (int mi = 0; mi < 4; mi++) aAddr[mi] = (wm * 64 + mi * 16 + l15) * 32 + l4 * 8;
  #pragma unroll
  for (int nj = 0; nj < 4; nj++) bAddr[nj] = (wn * 64 + nj * 16 + l15) * 32 + l4 * 8;

  float x2v[16];
  #pragma unroll
  for (int s = 0; s < 16; s++)
    x2v[s] = x2[brow + wm * 64 + (s >> 2) * 16 + l4 * 4 + (s & 3)];

  float b1[16], b2[16];
  int   bi[16];
  #pragma unroll
  for (int s = 0; s < 16; s++) { b1[s] = 1e30f; b2[s] = 1e30f; bi[s] = 0; }

  for (int c0 = 0; c0 < NCODE; c0 += 128) {
    f32x4 acc[4][4];
    #pragma unroll
    for (int mi = 0; mi < 4; mi++)
      #pragma unroll
      for (int nj = 0; nj < 4; nj++) acc[mi][nj] = (f32x4)0.0f;

    const size_t rowBase = (size_t)((isB ? c0 : brow) + laneRow) * NDIM + laneK;

    for (int k0 = 0; k0 < NDIM; k0 += 32) {
      __syncthreads();  // previous step's LDS reads complete
      const unsigned short* sb = gsrc0 + rowBase + k0;
      #pragma unroll
      for (int q = 0; q < 8; q++)
        gload16(sb + (size_t)q * 16 * NDIM, ldst + q * 512);
      __syncthreads();  // staging complete (vmcnt drained)

      bf16x8 ah4[4], al4[4];
      #pragma unroll
      for (int mi = 0; mi < 4; mi++) {
        ah4[mi] = *(const bf16x8*)(const void*)(Ah + aAddr[mi]);
        al4[mi] = *(const bf16x8*)(const void*)(Al + aAddr[mi]);
      }
      #pragma unroll
      for (int nj = 0; nj < 4; nj++) {
        bf16x8 bh = *(const bf16x8*)(const void*)(Bh + bAddr[nj]);
        bf16x8 bl = *(const bf16x8*)(const void*)(Bl + bAddr[nj]);
        #pragma unroll
        for (int mi = 0; mi < 4; mi++) {
          acc[mi][nj] = __builtin_amdgcn_mfma_f32_16x16x32_bf16(ah4[mi], bh, acc[mi][nj], 0, 0, 0);
          acc[mi][nj] = __builtin_amdgcn_mfma_f32_16x16x32_bf16(ah4[mi], bl, acc[mi][nj], 0, 0, 0);
          acc[mi][nj] = __builtin_amdgcn_mfma_f32_16x16x32_bf16(al4[mi], bh, acc[mi][nj], 0, 0, 0);
        }
      }
    }

    // argmin update for this 128-code chunk
    #pragma unroll
    for (int nj = 0; nj < 4; nj++) {
      int col = c0 + wn * 64 + nj * 16 + l15;
      float ev = e2[col];
      #pragma unroll
      for (int mi = 0; mi < 4; mi++) {
        #pragma unroll
        for (int r = 0; r < 4; r++) {
          float d = (x2v[mi * 4 + r] - 2.0f * acc[mi][nj][r]) + ev;
          int s = mi * 4 + r;
          if (d < b1[s]) { b2[s] = b1[s]; b1[s] = d; bi[s] = col; }
          else if (d < b2[s]) { b2[s] = d; }
        }
      }
    }
  }

  // reduce top-2 across the 16 column-lanes
  #pragma unroll
  for (int off = 8; off >= 1; off >>= 1) {
    #pragma unroll
    for (int s = 0; s < 16; s++) {
      float o1 = __shfl_xor(b1[s], off, 16);
      int   oi = __shfl_xor(bi[s], off, 16);
      float o2 = __shfl_xor(b2[s], off, 16);
      float n2 = fminf(fmaxf(b1[s], o1), fminf(b2[s], o2));
      if (o1 < b1[s] || (o1 == b1[s] && oi < bi[s])) { b1[s] = o1; bi[s] = oi; }
      b2[s] = n2;
    }
  }

  __syncthreads();
  if (l15 == 0) {
    #pragma unroll
    for (int s = 0; s < 16; s++) {
      int rowLocal = wm * 64 + (s >> 2) * 16 + l4 * 4 + (s & 3);
      redD[wn][rowLocal] = b1[s];
      redI[wn][rowLocal] = bi[s];
      redS[wn][rowLocal] = b2[s];
    }
  }
  __syncthreads();
  if (tid < 128) {
    float d0 = redD[0][tid], d1 = redD[1][tid];
    int   i0 = redI[0][tid], i1 = redI[1][tid];
    float s0 = redS[0][tid], s1 = redS[1][tid];
    float first; int fi;
    if (d1 < d0 || (d1 == d0 && i1 < i0)) { first = d1; fi = i1; }
    else                                  { first = d0; fi = i0; }
    float second = fminf(fmaxf(d0, d1), fminf(s0, s1));
    idxOut[brow + tid]    = fi;
    marginOut[brow + tid] = second - first;
  }
}

// exact recheck for tokens with tiny top-2 margin: one wave per token
__global__ void k_recheck(const float* __restrict__ x, const float* __restrict__ emb,
                          const float* __restrict__ x2, const float* __restrict__ e2,
                          const float* __restrict__ margin, int* __restrict__ idxArr) {
  int t    = (blockIdx.x * blockDim.x + threadIdx.x) >> 6;
  int lane = threadIdx.x & 63;
  if (t >= NTOK) return;
  if (margin[t] >= TAU) return;

  const float* xr = x + (size_t)t * NDIM + lane * 8;
  float4 xa = *(const float4*)xr;
  float4 xb = *(const float4*)(xr + 4);
  double x2d = (double)x2[t];
  double bestD = 1e300;
  int    bestI = 0;
  for (int c = 0; c < NCODE; c++) {
    const float* er = emb + (size_t)c * NDIM + lane * 8;
    float4 ea = *(const float4*)er;
    float4 eb = *(const float4*)(er + 4);
    float dot = xa.x * ea.x;
    dot = fmaf(xa.y, ea.y, dot);
    dot = fmaf(xa.z, ea.z, dot);
    dot = fmaf(xa.w, ea.w, dot);
    dot = fmaf(xb.x, eb.x, dot);
    dot = fmaf(xb.y, eb.y, dot);
    dot = fmaf(xb.z, eb.z, dot);
    dot = fmaf(xb.w, eb.w, dot);
    double d = (double)dot;
    #pragma unroll
    for (int off = 32; off >= 1; off >>= 1) d += __shfl_xor(d, off, 64);
    double dist = (x2d - 2.0 * d) + (double)e2[c];
    if (dist < bestD) { bestD = dist; bestI = c; }
  }
  if (lane == 0) idxArr[t] = bestI;
}

// ===================== fallback f32 argmin (small-ws path) =====================
#define BM 64
#define BN 64
#define BK 32
__launch_bounds__(256)
__global__ void k_argmin_f32(const float* __restrict__ x, const float* __restrict__ emb,
                             const float* __restrict__ x2, const float* __restrict__ e2,
                             int* __restrict__ idxOut) {
  __shared__ __align__(16) float xs[BK][BM + 4];
  __shared__ __align__(16) float es[BK][BN + 4];
  const int tid  = threadIdx.x;
  const int tx   = tid & 15;
  const int ty   = tid >> 4;
  const int brow = blockIdx.x * BM;
  const int lk   = tid & 7;
  const int lr   = tid >> 3;

  float x2v[4];
  #pragma unroll
  for (int i = 0; i < 4; i++) x2v[i] = x2[brow + ty * 4 + i];
  double best[4];
  int    bidx[4];
  #pragma unroll
  for (int i = 0; i < 4; i++) { best[i] = 1e300; bidx[i] = 0; }

  for (int c0 = 0; c0 < NCODE; c0 += BN) {
    float acc[4][4];
    #pragma unroll
    for (int i = 0; i < 4; i++)
      #pragma unroll
      for (int j = 0; j < 4; j++) acc[i][j] = 0.0f;
    for (int k0 = 0; k0 < NDIM; k0 += BK) {
      __syncthreads();
      float4 v0 = *(const float4*)&x  [(size_t)(brow + lr)      * NDIM + k0 + lk * 4];
      float4 v1 = *(const float4*)&x  [(size_t)(brow + lr + 32) * NDIM + k0 + lk * 4];
      float4 w0 = *(const float4*)&emb[(size_t)(c0   + lr)      * NDIM + k0 + lk * 4];
      float4 w1 = *(const float4*)&emb[(size_t)(c0   + lr + 32) * NDIM + k0 + lk * 4];
      float a0[4] = {v0.x, v0.y, v0.z, v0.w};
      float a1[4] = {v1.x, v1.y, v1.z, v1.w};
      float b0[4] = {w0.x, w0.y, w0.z, w0.w};
      float b1f[4] = {w1.x, w1.y, w1.z, w1.w};
      #pragma unroll
      for (int j = 0; j < 4; j++) {
        xs[lk * 4 + j][lr]      = a0[j];
        xs[lk * 4 + j][lr + 32] = a1[j];
        es[lk * 4 + j][lr]      = b0[j];
        es[lk * 4 + j][lr + 32] = b1f[j];
      }
      __syncthreads();
      #pragma unroll
      for (int k = 0; k < BK; k++) {
        const float4 av = *(const float4*)&xs[k][ty * 4];
        const float4 bv = *(const float4*)&es[k][tx * 4];
        const float ax[4] = {av.x, av.y, av.z, av.w};
        const float bx[4] = {bv.x, bv.y, bv.z, bv.w};
        #pragma unroll
        for (int i = 0; i < 4; i++)
          #pragma unroll
          for (int j = 0; j < 4; j++) acc[i][j] += ax[i] * bx[j];
      }
    }
    #pragma unroll
    for (int j = 0; j < 4; j++) {
      float e2v = e2[c0 + tx * 4 + j];
      int   ci  = c0 + tx * 4 + j;
      #pragma unroll
      for (int i = 0; i < 4; i++) {
        double d = ((double)x2v[i] - 2.0 * (double)acc[i][j]) + (double)e2v;
        if (d < best[i]) { best[i] = d; bidx[i] = ci; }
      }
    }
  }
  #pragma unroll
  for (int off = 8; off >= 1; off >>= 1) {
    #pragma unroll
    for (int i = 0; i < 4; i++) {
      double ob = __shfl_xor(best[i], off, 16);
      int    oi = __shfl_xor(bidx[i], off, 16);
      if (ob < best[i] || (ob == best[i] && oi < bidx[i])) { best[i] = ob; bidx[i] = oi; }
    }
  }
  if (tx == 0) {
    #pragma unroll
    for (int i = 0; i < 4; i++) idxOut[brow + ty * 4 + i] = bidx[i];
  }
}

// one wave per token: z, diff partial, csize histogram, csum scatter, codes
__global__ void k_quant(const float* __restrict__ x, const float* __restrict__ emb,
                        const int* __restrict__ idxArr, float* __restrict__ z,
                        float* __restrict__ csum, float* __restrict__ csize,
                        float* __restrict__ diffSum, float* __restrict__ codesOut) {
  int t    = (blockIdx.x * blockDim.x + threadIdx.x) >> 6;
  int lane = threadIdx.x & 63;
  if (t >= NTOK) return;
  int idx = idxArr[t];
  const float* xr = x   + (size_t)t   * NDIM;
  const float* er = emb + (size_t)idx * NDIM;
  float* zr = z    + (size_t)t   * NDIM;
  float* cr = csum + (size_t)idx * NDIM;
  float part = 0.0f;
  #pragma unroll
  for (int b = 0; b < 2; b++) {
    int k = lane * 8 + b * 4;
    float4 q  = *(const float4*)(er + k);
    float4 xv = *(const float4*)(xr + k);
    float4 dv; dv.x = q.x - xv.x; dv.y = q.y - xv.y; dv.z = q.z - xv.z; dv.w = q.w - xv.w;
    float4 zv; zv.x = xv.x + dv.x; zv.y = xv.y + dv.y; zv.z = xv.z + dv.z; zv.w = xv.w + dv.w;
    *(float4*)(zr + k) = zv;
    part += ((dv.x*dv.x + dv.y*dv.y) + (dv.z*dv.z + dv.w*dv.w));
    atomAddF(cr + k + 0, xv.x);
    atomAddF(cr + k + 1, xv.y);
    atomAddF(cr + k + 2, xv.z);
    atomAddF(cr + k + 3, xv.w);
  }
  #pragma unroll
  for (int off = 32; off >= 1; off >>= 1) part += __shfl_xor(part, off, 64);
  if (lane == 0) {
    atomAddF(diffSum, part);
    atomAddF(csize + idx, 1.0f);
    codesOut[t] = (float)idx;
  }
}

__global__ void k_stats(const float* __restrict__ clusterSize, const float* __restrict__ csize,
                        const float* __restrict__ diffSum, float* __restrict__ out,
                        float* __restrict__ nOut) {
  const float OMD = (float)(1.0 - 0.995);
  int tid = threadIdx.x;
  float ln = 0.0f, lu = 0.0f, le = 0.0f;
  for (int i = tid; i < NCODE; i += 256) {
    float c  = csize[i];
    float ns = 0.995f * clusterSize[i] + OMD * c;
    out[OFF_SIZE + i] = ns;
    ln += ns;
    if (ns >= 0.99f) lu += 1.0f;
    float pr = c * (1.0f / 32768.0f);
    le += pr * logf(pr + 1e-5f);
  }
  #pragma unroll
  for (int off = 32; off >= 1; off >>= 1) {
    ln += __shfl_xor(ln, off, 64);
    lu += __shfl_xor(lu, off, 64);
    le += __shfl_xor(le, off, 64);
  }
  __shared__ float sn[4], su[4], se[4];
  int w = tid >> 6;
  if ((tid & 63) == 0) { sn[w] = ln; su[w] = lu; se[w] = le; }
  __syncthreads();
  if (tid == 0) {
    float n = (sn[0] + sn[1]) + (sn[2] + sn[3]);
    float u = (su[0] + su[1]) + (su[2] + su[3]);
    float e = (se[0] + se[1]) + (se[2] + se[3]);
    nOut[0] = n;
    out[OFF_DIFF]  = diffSum[0] * (1.0f / 16777216.0f);
    out[OFF_AVGU]  = u * (1.0f / 4096.0f);
    out[OFF_USAGE] = u;
    out[OFF_ENT]   = -e;
  }
}

__global__ void k_final(const float* __restrict__ clusterSum, const float* __restrict__ newSize,
                        const float* __restrict__ nPtr, float* __restrict__ sumIO,
                        float* __restrict__ embOut) {
  const float OMD = (float)(1.0 - 0.995);
  int i = blockIdx.x * blockDim.x + threadIdx.x;
  if (i >= NCODE * NDIM) return;
  int c = i >> 9;
  float n   = nPtr[0];
  float raw = sumIO[i];
  float ns  = 0.995f * clusterSum[i] + OMD * raw;
  sumIO[i] = ns;
  float sz  = newSize[c];
  float cnt = (sz + 1e-4f) / (n + 0.4096f) * n;
  float center = ns / cnt;
  embOut[i] = (sz >= 0.99f) ? center : 0.0f;
}

extern "C" void kernel_launch(void* const* d_in, const int* in_sizes, int n_in,
                              void* d_out, int out_size, void* d_ws, size_t ws_size,
                              hipStream_t stream) {
  const float* x   = (const float*)d_in[0];
  const float* emb = (const float*)d_in[1];
  const float* csz = (const float*)d_in[2];
  const float* csm = (const float*)d_in[3];
  float* out = (float*)d_out;

  float* wsf     = (float*)d_ws;
  float* diffSum = wsf;                      // [0]
  float* nScal   = wsf + 1;                  // [1]
  float* csize   = wsf + 64;                 // 4096
  float* x2      = wsf + 64 + NCODE;         // 32768
  float* e2      = x2 + NTOK;                // 4096
  int*   idxArr  = (int*)(e2 + NCODE);       // 32768
  float* margin  = (float*)(idxArr + NTOK);  // 32768
  unsigned short* xh = (unsigned short*)(margin + NTOK);           // 16.7M ushort
  unsigned short* xl = xh + (size_t)NTOK * NDIM;
  unsigned short* eh = xl + (size_t)NTOK * NDIM;
  unsigned short* el = eh + (size_t)NCODE * NDIM;

  const size_t need = (size_t)(el + (size_t)NCODE * NDIM - (unsigned short*)d_ws) * 2;

  k_zero<<<(NCODE * NDIM + 255) / 256, 256, 0, stream>>>(out + OFF_SUM, NCODE * NDIM);
  k_zero<<<(64 + NCODE + 255) / 256, 256, 0, stream>>>(wsf, 64 + NCODE);
  k_rowsq<<<NCODE / 4, 256, 0, stream>>>(emb, e2, NCODE);
  k_rowsq<<<NTOK / 4, 256, 0, stream>>>(x, x2, NTOK);

  if (ws_size >= need) {
    k_split<<<(NTOK * NDIM / 8 + 255) / 256, 256, 0, stream>>>(x, xh, xl, NTOK * NDIM / 8);
    k_split<<<(NCODE * NDIM / 8 + 255) / 256, 256, 0, stream>>>(emb, eh, el, NCODE * NDIM / 8);
    k_argmin_mfma<<<NTOK / 128, 256, 0, stream>>>(xh, xl, eh, el, x2, e2, idxArr, margin);
    k_recheck<<<NTOK * 64 / 256, 256, 0, stream>>>(x, emb, x2, e2, margin, idxArr);
  } else {
    k_argmin_f32<<<NTOK / BM, 256, 0, stream>>>(x, emb, x2, e2, idxArr);
  }

  k_quant<<<NTOK / 4, 256, 0, stream>>>(x, emb, idxArr, out + OFF_Z, out + OFF_SUM, csize, diffSum,
                                        out + OFF_CODES);
  k_stats<<<1, 256, 0, stream>>>(csz, csize, diffSum, out, nScal);
  k_final<<<(NCODE * NDIM + 255) / 256, 256, 0, stream>>>(csm, out + OFF_SIZE, nScal, out + OFF_SUM, out + OFF_EMB);
}

// Round 3
// 1546.063 us; speedup vs baseline: 2.3581x; 2.3581x over previous
//
#include <hip/hip_runtime.h>
#include <math.h>

#define NTOK 32768
#define NDIM 512
#define NCODE 4096
#define NHALF 2048

// output layout (flat f32, reference tuple order)
#define OFF_Z      0
#define OFF_DIFF   16777216
#define OFF_CODES  16777217
#define OFF_EMB    16809985
#define OFF_SIZE   18907137
#define OFF_SUM    18911233
#define OFF_AVGU   21008385
#define OFF_USAGE  21008386
#define OFF_ENT    21008387

#define TAU 0.01f

typedef _Float16 f16x8 __attribute__((ext_vector_type(8)));
typedef float f32x4 __attribute__((ext_vector_type(4)));
typedef unsigned short ushort8 __attribute__((ext_vector_type(8)));
typedef unsigned int u32;

__device__ __forceinline__ void atomAddF(float* p, float v) {
  unsafeAtomicAdd(p, v);
}

__device__ __forceinline__ void gload16(const void* g, void* l) {
  __builtin_amdgcn_global_load_lds((const __attribute__((address_space(1))) u32*)g,
                                   (__attribute__((address_space(3))) u32*)l, 16, 0, 0);
}

// involutive 16B-chunk swizzle: bits0-2 ^= bits3-5 (spreads 64B rows across 8 bank-sets)
__device__ __forceinline__ int swz16(int c) { return c ^ ((c >> 3) & 7); }

__global__ void k_zero(float* __restrict__ p, int n) {
  int i = blockIdx.x * blockDim.x + threadIdx.x;
  if (i < n) p[i] = 0.0f;
}

// split f32 into f16 hi + f16 lo (8 elements / thread)
__global__ void k_split(const float* __restrict__ in, unsigned short* __restrict__ hi,
                        unsigned short* __restrict__ lo, int n8) {
  int i = blockIdx.x * blockDim.x + threadIdx.x;
  if (i >= n8) return;
  const float4* p = (const float4*)(in + (size_t)i * 8);
  float4 a = p[0], b = p[1];
  float v[8] = {a.x, a.y, a.z, a.w, b.x, b.y, b.z, b.w};
  ushort8 h, lw;
  #pragma unroll
  for (int j = 0; j < 8; j++) {
    float f = v[j];
    _Float16 hb = (_Float16)f;
    float hf = (float)hb;
    _Float16 lb = (_Float16)(f - hf);
    h[j]  = __builtin_bit_cast(unsigned short, hb);
    lw[j] = __builtin_bit_cast(unsigned short, lb);
  }
  *(ushort8*)(hi + (size_t)i * 8) = h;
  *(ushort8*)(lo + (size_t)i * 8) = lw;
}

// one wave per row: sum of squares of a 512-float row (for emb only)
__global__ void k_rowsq(const float* __restrict__ rows, float* __restrict__ out, int nrows) {
  int gw   = (blockIdx.x * blockDim.x + threadIdx.x) >> 6;
  int lane = threadIdx.x & 63;
  if (gw >= nrows) return;
  const float* r = rows + (size_t)gw * NDIM + lane * 8;
  float4 a = *(const float4*)r;
  float4 b = *(const float4*)(r + 4);
  float s = ((a.x*a.x + a.y*a.y) + (a.z*a.z + a.w*a.w))
          + ((b.x*b.x + b.y*b.y) + (b.z*b.z + b.w*b.w));
  #pragma unroll
  for (int off = 32; off >= 1; off >>= 1) s += __shfl_xor(s, off, 64);
  if (lane == 0) out[gw] = s;
}

// ===================== MFMA argmin =====================
// grid (128, 2): 256 tokens per block-x, code half per block-y.
// 8 waves (512 thr), wave grid 4(token)x2(code). dist = e2 - 2*dot (x2 dropped).
// dot via f16 hi/lo: hh + hl + lh (3 MFMAs), f32 accumulate.
__launch_bounds__(512)
__global__ void k_argmin_mfma(const unsigned short* __restrict__ xh, const unsigned short* __restrict__ xl,
                              const unsigned short* __restrict__ eh, const unsigned short* __restrict__ el,
                              const float* __restrict__ e2,
                              float* __restrict__ pb1, int* __restrict__ pi1, float* __restrict__ pb2) {
  __shared__ __align__(16) unsigned short Ah[256 * 32];
  __shared__ __align__(16) unsigned short Al[256 * 32];
  __shared__ __align__(16) unsigned short Bh[128 * 32];
  __shared__ __align__(16) unsigned short Bl[128 * 32];
  __shared__ float redD[2][256];
  __shared__ int   redI[2][256];
  __shared__ float redS[2][256];

  const int tid = threadIdx.x;
  const int w   = tid >> 6;
  const int l   = tid & 63;
  const int wm  = w >> 1;     // 0..3 token quarter (64 rows)
  const int wn  = w & 1;      // 0..1 code half (64 cols of 128)
  const int l15 = l & 15;
  const int l4  = l >> 4;
  const int brow  = blockIdx.x * 256;
  const int cbase = blockIdx.y * NHALF;

  // fragment LDS chunk addrs (16B chunks), swizzled
  int aOff[4], bOff[4];
  #pragma unroll
  for (int mi = 0; mi < 4; mi++) aOff[mi] = swz16((wm * 64 + mi * 16 + l15) * 4 + l4) * 8;
  #pragma unroll
  for (int nj = 0; nj < 4; nj++) bOff[nj] = swz16((wn * 64 + nj * 16 + l15) * 4 + l4) * 8;

  // staging chunk -> (row, seg) with inverse(=same) swizzle on global source
  int aU0 = swz16(w * 64 + l), aU1 = swz16((w + 8) * 64 + l), bU = swz16(w * 64 + l);
  const int aR0 = aU0 >> 2, aS0 = (aU0 & 3) * 8;
  const int aR1 = aU1 >> 2, aS1 = (aU1 & 3) * 8;
  const int bR  = bU  >> 2, bS  = (bU  & 3) * 8;
  const int aC0 = (w * 64 + l) * 8, aC1 = ((w + 8) * 64 + l) * 8, bC = (w * 64 + l) * 8;

  float b1[16], b2[16];
  int   bi[16];
  #pragma unroll
  for (int s = 0; s < 16; s++) { b1[s] = 1e30f; b2[s] = 1e30f; bi[s] = 0; }

  for (int c0 = cbase; c0 < cbase + NHALF; c0 += 128) {
    f32x4 acc[4][4];
    #pragma unroll
    for (int mi = 0; mi < 4; mi++)
      #pragma unroll
      for (int nj = 0; nj < 4; nj++) acc[mi][nj] = (f32x4)0.0f;

    for (int k0 = 0; k0 < NDIM; k0 += 32) {
      __syncthreads();  // prior LDS reads complete
      gload16(xh + (size_t)(brow + aR0) * NDIM + k0 + aS0, Ah + aC0);
      gload16(xh + (size_t)(brow + aR1) * NDIM + k0 + aS1, Ah + aC1);
      gload16(xl + (size_t)(brow + aR0) * NDIM + k0 + aS0, Al + aC0);
      gload16(xl + (size_t)(brow + aR1) * NDIM + k0 + aS1, Al + aC1);
      gload16(eh + (size_t)(c0 + bR) * NDIM + k0 + bS, Bh + bC);
      gload16(el + (size_t)(c0 + bR) * NDIM + k0 + bS, Bl + bC);
      __syncthreads();  // staging visible to all waves

      f16x8 ah4[4], al4[4];
      #pragma unroll
      for (int mi = 0; mi < 4; mi++) {
        ah4[mi] = *(const f16x8*)(const void*)(Ah + aOff[mi]);
        al4[mi] = *(const f16x8*)(const void*)(Al + aOff[mi]);
      }
      #pragma unroll
      for (int nj = 0; nj < 4; nj++) {
        f16x8 bh = *(const f16x8*)(const void*)(Bh + bOff[nj]);
        f16x8 bl = *(const f16x8*)(const void*)(Bl + bOff[nj]);
        #pragma unroll
        for (int mi = 0; mi < 4; mi++) {
          acc[mi][nj] = __builtin_amdgcn_mfma_f32_16x16x32_f16(ah4[mi], bh, acc[mi][nj], 0, 0, 0);
          acc[mi][nj] = __builtin_amdgcn_mfma_f32_16x16x32_f16(ah4[mi], bl, acc[mi][nj], 0, 0, 0);
          acc[mi][nj] = __builtin_amdgcn_mfma_f32_16x16x32_f16(al4[mi], bh, acc[mi][nj], 0, 0, 0);
        }
      }
    }

    #pragma unroll
    for (int nj = 0; nj < 4; nj++) {
      int col  = c0 + wn * 64 + nj * 16 + l15;
      float ev = e2[col];
      #pragma unroll
      for (int mi = 0; mi < 4; mi++) {
        #pragma unroll
        for (int r = 0; r < 4; r++) {
          float d = ev - 2.0f * acc[mi][nj][r];
          int s = mi * 4 + r;
          if (d < b1[s]) { b2[s] = b1[s]; b1[s] = d; bi[s] = col; }
          else if (d < b2[s]) { b2[s] = d; }
        }
      }
    }
  }

  // reduce top-2 across the 16 column-lanes
  #pragma unroll
  for (int off = 8; off >= 1; off >>= 1) {
    #pragma unroll
    for (int s = 0; s < 16; s++) {
      float o1 = __shfl_xor(b1[s], off, 16);
      int   oi = __shfl_xor(bi[s], off, 16);
      float o2 = __shfl_xor(b2[s], off, 16);
      float n2 = fminf(fmaxf(b1[s], o1), fminf(b2[s], o2));
      if (o1 < b1[s] || (o1 == b1[s] && oi < bi[s])) { b1[s] = o1; bi[s] = oi; }
      b2[s] = n2;
    }
  }

  __syncthreads();
  if (l15 == 0) {
    #pragma unroll
    for (int s = 0; s < 16; s++) {
      int rowLocal = wm * 64 + (s >> 2) * 16 + l4 * 4 + (s & 3);
      redD[wn][rowLocal] = b1[s];
      redI[wn][rowLocal] = bi[s];
      redS[wn][rowLocal] = b2[s];
    }
  }
  __syncthreads();
  if (tid < 256) {
    float d0 = redD[0][tid], d1 = redD[1][tid];
    int   i0 = redI[0][tid], i1 = redI[1][tid];
    float s0 = redS[0][tid], s1 = redS[1][tid];
    float first; int fi;
    if (d1 < d0 || (d1 == d0 && i1 < i0)) { first = d1; fi = i1; }
    else                                  { first = d0; fi = i0; }
    float second = fminf(fmaxf(d0, d1), fminf(s0, s1));
    size_t o = (size_t)blockIdx.y * NTOK + brow + tid;
    pb1[o] = first; pi1[o] = fi; pb2[o] = second;
  }
}

// combine the two code-half partials; append low-margin tokens to recheck list
__global__ void k_combine(const float* __restrict__ pb1, const int* __restrict__ pi1,
                          const float* __restrict__ pb2, int* __restrict__ idxArr,
                          int* __restrict__ cnt, int* __restrict__ list) {
  int t = blockIdx.x * blockDim.x + threadIdx.x;
  if (t >= NTOK) return;
  float d0 = pb1[t], d1 = pb1[NTOK + t];
  int   i0 = pi1[t], i1 = pi1[NTOK + t];
  float s0 = pb2[t], s1 = pb2[NTOK + t];
  float first; int fi;
  if (d1 < d0) { first = d1; fi = i1; }
  else         { first = d0; fi = i0; }
  float second = fminf(fmaxf(d0, d1), fminf(s0, s1));
  idxArr[t] = fi;
  if (second - first < TAU) {
    int p = atomicAdd(cnt, 1);
    list[p] = t;
  }
}

// exact recheck: one block per flagged token, codes split across 256 threads
__global__ void k_recheck2(const float* __restrict__ x, const float* __restrict__ emb,
                           const float* __restrict__ e2, const int* __restrict__ cnt,
                           const int* __restrict__ list, int* __restrict__ idxArr) {
  __shared__ float xs[NDIM];
  __shared__ double bd[256];
  __shared__ int    bix[256];
  int n = cnt[0];
  for (int ti = blockIdx.x; ti < n; ti += gridDim.x) {
    int t = list[ti];
    __syncthreads();
    for (int d = threadIdx.x; d < NDIM; d += 256) xs[d] = x[(size_t)t * NDIM + d];
    __syncthreads();
    double bD = 1e300; int bI = 0x7fffffff;
    for (int c = threadIdx.x; c < NCODE; c += 256) {
      const float* er = emb + (size_t)c * NDIM;
      double a0 = 0.0, a1 = 0.0, a2 = 0.0, a3 = 0.0;
      for (int d = 0; d < NDIM; d += 4) {
        float4 e4 = *(const float4*)(er + d);
        a0 += (double)xs[d]     * (double)e4.x;
        a1 += (double)xs[d + 1] * (double)e4.y;
        a2 += (double)xs[d + 2] * (double)e4.z;
        a3 += (double)xs[d + 3] * (double)e4.w;
      }
      double dist = (double)e2[c] - 2.0 * ((a0 + a1) + (a2 + a3));
      if (dist < bD || (dist == bD && c < bI)) { bD = dist; bI = c; }
    }
    bd[threadIdx.x] = bD; bix[threadIdx.x] = bI;
    __syncthreads();
    for (int s = 128; s > 0; s >>= 1) {
      if (threadIdx.x < s) {
        double od = bd[threadIdx.x + s]; int oi = bix[threadIdx.x + s];
        if (od < bd[threadIdx.x] || (od == bd[threadIdx.x] && oi < bix[threadIdx.x])) {
          bd[threadIdx.x] = od; bix[threadIdx.x] = oi;
        }
      }
      __syncthreads();
    }
    if (threadIdx.x == 0) idxArr[t] = bix[0];
  }
}

// ===================== fallback f32 argmin (small-ws path) =====================
#define BM 64
#define BN 64
#define BK 32
__launch_bounds__(256)
__global__ void k_argmin_f32(const float* __restrict__ x, const float* __restrict__ emb,
                             const float* __restrict__ e2, int* __restrict__ idxOut) {
  __shared__ __align__(16) float xs[BK][BM + 4];
  __shared__ __align__(16) float es[BK][BN + 4];
  const int tid  = threadIdx.x;
  const int tx   = tid & 15;
  const int ty   = tid >> 4;
  const int brow = blockIdx.x * BM;
  const int lk   = tid & 7;
  const int lr   = tid >> 3;

  double best[4];
  int    bidx[4];
  #pragma unroll
  for (int i = 0; i < 4; i++) { best[i] = 1e300; bidx[i] = 0; }

  for (int c0 = 0; c0 < NCODE; c0 += BN) {
    float acc[4][4];
    #pragma unroll
    for (int i = 0; i < 4; i++)
      #pragma unroll
      for (int j = 0; j < 4; j++) acc[i][j] = 0.0f;
    for (int k0 = 0; k0 < NDIM; k0 += BK) {
      __syncthreads();
      float4 v0 = *(const float4*)&x  [(size_t)(brow + lr)      * NDIM + k0 + lk * 4];
      float4 v1 = *(const float4*)&x  [(size_t)(brow + lr + 32) * NDIM + k0 + lk * 4];
      float4 w0 = *(const float4*)&emb[(size_t)(c0   + lr)      * NDIM + k0 + lk * 4];
      float4 w1 = *(const float4*)&emb[(size_t)(c0   + lr + 32) * NDIM + k0 + lk * 4];
      float a0[4] = {v0.x, v0.y, v0.z, v0.w};
      float a1[4] = {v1.x, v1.y, v1.z, v1.w};
      float b0[4] = {w0.x, w0.y, w0.z, w0.w};
      float b1f[4] = {w1.x, w1.y, w1.z, w1.w};
      #pragma unroll
      for (int j = 0; j < 4; j++) {
        xs[lk * 4 + j][lr]      = a0[j];
        xs[lk * 4 + j][lr + 32] = a1[j];
        es[lk * 4 + j][lr]      = b0[j];
        es[lk * 4 + j][lr + 32] = b1f[j];
      }
      __syncthreads();
      #pragma unroll
      for (int k = 0; k < BK; k++) {
        const float4 av = *(const float4*)&xs[k][ty * 4];
        const float4 bv = *(const float4*)&es[k][tx * 4];
        const float ax[4] = {av.x, av.y, av.z, av.w};
        const float bx[4] = {bv.x, bv.y, bv.z, bv.w};
        #pragma unroll
        for (int i = 0; i < 4; i++)
          #pragma unroll
          for (int j = 0; j < 4; j++) acc[i][j] += ax[i] * bx[j];
      }
    }
    #pragma unroll
    for (int j = 0; j < 4; j++) {
      float e2v = e2[c0 + tx * 4 + j];
      int   ci  = c0 + tx * 4 + j;
      #pragma unroll
      for (int i = 0; i < 4; i++) {
        double d = (double)e2v - 2.0 * (double)acc[i][j];
        if (d < best[i]) { best[i] = d; bidx[i] = ci; }
      }
    }
  }
  #pragma unroll
  for (int off = 8; off >= 1; off >>= 1) {
    #pragma unroll
    for (int i = 0; i < 4; i++) {
      double ob = __shfl_xor(best[i], off, 16);
      int    oi = __shfl_xor(bidx[i], off, 16);
      if (ob < best[i] || (ob == best[i] && oi < bidx[i])) { best[i] = ob; bidx[i] = oi; }
    }
  }
  if (tx == 0) {
    #pragma unroll
    for (int i = 0; i < 4; i++) idxOut[brow + ty * 4 + i] = bidx[i];
  }
}

// one wave per token: z, diff partial, csize histogram, csum scatter, codes
__global__ void k_quant(const float* __restrict__ x, const float* __restrict__ emb,
                        const int* __restrict__ idxArr, float* __restrict__ z,
                        float* __restrict__ csum, float* __restrict__ csize,
                        float* __restrict__ diffSum, float* __restrict__ codesOut) {
  int t    = (blockIdx.x * blockDim.x + threadIdx.x) >> 6;
  int lane = threadIdx.x & 63;
  if (t >= NTOK) return;
  int idx = idxArr[t];
  const float* xr = x   + (size_t)t   * NDIM;
  const float* er = emb + (size_t)idx * NDIM;
  float* zr = z    + (size_t)t   * NDIM;
  float* cr = csum + (size_t)idx * NDIM;
  float part = 0.0f;
  #pragma unroll
  for (int b = 0; b < 2; b++) {
    int k = lane * 8 + b * 4;
    float4 q  = *(const float4*)(er + k);
    float4 xv = *(const float4*)(xr + k);
    float4 dv; dv.x = q.x - xv.x; dv.y = q.y - xv.y; dv.z = q.z - xv.z; dv.w = q.w - xv.w;
    float4 zv; zv.x = xv.x + dv.x; zv.y = xv.y + dv.y; zv.z = xv.z + dv.z; zv.w = xv.w + dv.w;
    *(float4*)(zr + k) = zv;
    part += ((dv.x*dv.x + dv.y*dv.y) + (dv.z*dv.z + dv.w*dv.w));
    atomAddF(cr + k + 0, xv.x);
    atomAddF(cr + k + 1, xv.y);
    atomAddF(cr + k + 2, xv.z);
    atomAddF(cr + k + 3, xv.w);
  }
  #pragma unroll
  for (int off = 32; off >= 1; off >>= 1) part += __shfl_xor(part, off, 64);
  if (lane == 0) {
    atomAddF(diffSum, part);
    atomAddF(csize + idx, 1.0f);
    codesOut[t] = (float)idx;
  }
}

__global__ void k_stats(const float* __restrict__ clusterSize, const float* __restrict__ csize,
                        const float* __restrict__ diffSum, float* __restrict__ out,
                        float* __restrict__ nOut) {
  const float OMD = (float)(1.0 - 0.995);
  int tid = threadIdx.x;
  float ln = 0.0f, lu = 0.0f, le = 0.0f;
  for (int i = tid; i < NCODE; i += 256) {
    float c  = csize[i];
    float ns = 0.995f * clusterSize[i] + OMD * c;
    out[OFF_SIZE + i] = ns;
    ln += ns;
    if (ns >= 0.99f) lu += 1.0f;
    float pr = c * (1.0f / 32768.0f);
    le += pr * logf(pr + 1e-5f);
  }
  #pragma unroll
  for (int off = 32; off >= 1; off >>= 1) {
    ln += __shfl_xor(ln, off, 64);
    lu += __shfl_xor(lu, off, 64);
    le += __shfl_xor(le, off, 64);
  }
  __shared__ float sn[4], su[4], se[4];
  int w = tid >> 6;
  if ((tid & 63) == 0) { sn[w] = ln; su[w] = lu; se[w] = le; }
  __syncthreads();
  if (tid == 0) {
    float n = (sn[0] + sn[1]) + (sn[2] + sn[3]);
    float u = (su[0] + su[1]) + (su[2] + su[3]);
    float e = (se[0] + se[1]) + (se[2] + se[3]);
    nOut[0] = n;
    out[OFF_DIFF]  = diffSum[0] * (1.0f / 16777216.0f);
    out[OFF_AVGU]  = u * (1.0f / 4096.0f);
    out[OFF_USAGE] = u;
    out[OFF_ENT]   = -e;
  }
}

__global__ void k_final(const float* __restrict__ clusterSum, const float* __restrict__ newSize,
                        const float* __restrict__ nPtr, float* __restrict__ sumIO,
                        float* __restrict__ embOut) {
  const float OMD = (float)(1.0 - 0.995);
  int i = blockIdx.x * blockDim.x + threadIdx.x;
  if (i >= NCODE * NDIM) return;
  int c = i >> 9;
  float n   = nPtr[0];
  float raw = sumIO[i];
  float ns  = 0.995f * clusterSum[i] + OMD * raw;
  sumIO[i] = ns;
  float sz  = newSize[c];
  float cnt = (sz + 1e-4f) / (n + 0.4096f) * n;
  float center = ns / cnt;
  embOut[i] = (sz >= 0.99f) ? center : 0.0f;
}

extern "C" void kernel_launch(void* const* d_in, const int* in_sizes, int n_in,
                              void* d_out, int out_size, void* d_ws, size_t ws_size,
                              hipStream_t stream) {
  const float* x   = (const float*)d_in[0];
  const float* emb = (const float*)d_in[1];
  const float* csz = (const float*)d_in[2];
  const float* csm = (const float*)d_in[3];
  float* out = (float*)d_out;

  float* wsf     = (float*)d_ws;
  float* diffSum = wsf;                      // [0]
  float* nScal   = wsf + 1;                  // [1]
  int*   flagCnt = (int*)(wsf + 2);          // [2]
  float* csize   = wsf + 64;                 // 4096
  float* e2      = csize + NCODE;            // 4096
  int*   idxArr  = (int*)(e2 + NCODE);       // 32768
  int*   list    = idxArr + NTOK;            // 32768
  float* pb1     = (float*)(list + NTOK);    // 2*32768
  int*   pi1     = (int*)(pb1 + 2 * NTOK);   // 2*32768
  float* pb2     = (float*)(pi1 + 2 * NTOK); // 2*32768
  unsigned short* xh = (unsigned short*)(pb2 + 2 * NTOK);
  unsigned short* xl = xh + (size_t)NTOK * NDIM;
  unsigned short* eh = xl + (size_t)NTOK * NDIM;
  unsigned short* el = eh + (size_t)NCODE * NDIM;

  const size_t need = (size_t)((char*)(el + (size_t)NCODE * NDIM) - (char*)d_ws);

  k_zero<<<(NCODE * NDIM + 255) / 256, 256, 0, stream>>>(out + OFF_SUM, NCODE * NDIM);
  k_zero<<<(64 + NCODE + 255) / 256, 256, 0, stream>>>(wsf, 64 + NCODE);
  k_rowsq<<<NCODE / 4, 256, 0, stream>>>(emb, e2, NCODE);

  if (ws_size >= need) {
    k_split<<<(NTOK * NDIM / 8 + 255) / 256, 256, 0, stream>>>(x, xh, xl, NTOK * NDIM / 8);
    k_split<<<(NCODE * NDIM / 8 + 255) / 256, 256, 0, stream>>>(emb, eh, el, NCODE * NDIM / 8);
    k_argmin_mfma<<<dim3(NTOK / 256, 2), 512, 0, stream>>>(xh, xl, eh, el, e2, pb1, pi1, pb2);
    k_combine<<<NTOK / 256, 256, 0, stream>>>(pb1, pi1, pb2, idxArr, flagCnt, list);
    k_recheck2<<<256, 256, 0, stream>>>(x, emb, e2, flagCnt, list, idxArr);
  } else {
    k_argmin_f32<<<NTOK / BM, 256, 0, stream>>>(x, emb, e2, idxArr);
  }

  k_quant<<<NTOK / 4, 256, 0, stream>>>(x, emb, idxArr, out + OFF_Z, out + OFF_SUM, csize, diffSum,
                                        out + OFF_CODES);
  k_stats<<<1, 256, 0, stream>>>(csz, csize, diffSum, out, nScal);
  k_final<<<(NCODE * NDIM + 255) / 256, 256, 0, stream>>>(csm, out + OFF_SIZE, nScal, out + OFF_SUM, out + OFF_EMB);
}